// Round 13
// baseline (798.283 us; speedup 1.0000x reference)
//
#include <hip/hip_runtime.h>
#include <hip/hip_bf16.h>

#define B_SZ 8192
#define S_DIM 512
#define H_DIM 1024
#define E_DIM 256
#define A_DIM 32

typedef __attribute__((ext_vector_type(4))) float f32x4;
typedef __attribute__((ext_vector_type(8))) __bf16 bf16x8;
typedef __attribute__((ext_vector_type(4))) int i32x4;
typedef __attribute__((ext_vector_type(8))) int i32x8;

using as1_void = __attribute__((address_space(1))) void;
using as3_void = __attribute__((address_space(3))) void;

__device__ __forceinline__ unsigned short f2bfu(float f) {
  unsigned u = __builtin_bit_cast(unsigned, f);
  unsigned r = (u + 0x7FFFu + ((u >> 16) & 1u)) >> 16;
  return (unsigned short)r;
}
__device__ __forceinline__ float bf2f(unsigned short x) {
  unsigned u = ((unsigned)x) << 16;
  return __builtin_bit_cast(float, u);
}
// f32 -> OCP e4m3 via HW packed convert (byte 0)
__device__ __forceinline__ unsigned char f2fp8(float f) {
  return (unsigned char)(__builtin_amdgcn_cvt_pk_fp8_f32(f, f, 0, false) & 0xFF);
}

// 16-lane xor-butterfly sum via DPP (VALU pipe, no LDS traffic).
__device__ __forceinline__ float row16_sum(float s) {
  float t;
  t = __builtin_bit_cast(float, __builtin_amdgcn_update_dpp(
          0, __builtin_bit_cast(int, s), 0xB1, 0xF, 0xF, true));
  s += t;
  t = __builtin_bit_cast(float, __builtin_amdgcn_update_dpp(
          0, __builtin_bit_cast(int, s), 0x4E, 0xF, 0xF, true));
  s += t;
  t = __builtin_bit_cast(float, __builtin_amdgcn_update_dpp(
          0, __builtin_bit_cast(int, s), 0x141, 0xF, 0xF, true));
  s += t;
  t = __builtin_bit_cast(float, __builtin_amdgcn_update_dpp(
          0, __builtin_bit_cast(int, s), 0x140, 0xF, 0xF, true));
  s += t;
  return s;
}

// ---------------- Kernel A: light prep (conv + small transposes + bias packs) ------------
// [0,4096): conv states->st_bf; [4096,5376): wcat transposes; [5376,5386): bcat;
// [5386,5418): bperm bias_p.
#define PREPA_BLOCKS 5418
__global__ void prepA_kernel(const float* __restrict__ states, const float* __restrict__ hw1_w1,
                             const float* __restrict__ hwf_w1, const float* __restrict__ hb1_w,
                             const float* __restrict__ v_w1, const float* __restrict__ hw1_b1,
                             const float* __restrict__ hwf_b1, const float* __restrict__ hb1_b,
                             const float* __restrict__ v_b1, const float* __restrict__ hw1_b2,
                             unsigned short* __restrict__ st_bf, unsigned short* __restrict__ wcat,
                             float* __restrict__ bcatp, float* __restrict__ bias_p) {
  __shared__ float t[32][33];
  const int tid = threadIdx.x;
  int b = blockIdx.x;
  if (b < 4096) {  // conv
    int idx = b * 1024 + tid * 4;
    const float4 v = *(const float4*)(states + idx);
    ushort4 o;
    o.x = f2bfu(v.x); o.y = f2bfu(v.y); o.z = f2bfu(v.z); o.w = f2bfu(v.w);
    *(ushort4*)(st_bf + idx) = o;
    return;
  }
  b -= 4096;
  if (b >= 1280) {  // bias packs
    b -= 1280;
    if (b < 10) {
      int i = b * 256 + tid;
      if (i < 2560) {
        float v;
        if (i < 1024) v = hw1_b1[i];
        else if (i < 2048) v = hwf_b1[i - 1024];
        else if (i < 2304) v = hb1_b[i - 2048];
        else v = v_b1[i - 2304];
        bcatp[i] = v;
      }
    } else {
      int n = (b - 10) * 256 + tid;
      bias_p[n] = hw1_b2[((n & 31) << 8) + (n >> 5)];
    }
    return;
  }
  // wcat transposes (K=512 weights -> B^T bf16)
  const float* src;
  unsigned short* dst;
  int C, tile;
  if (b < 512) { src = hw1_w1; dst = wcat; C = 1024; tile = b; }
  else if (b < 1024) { src = hwf_w1; dst = wcat + (size_t)1024 * 512; C = 1024; tile = b - 512; }
  else if (b < 1152) { src = hb1_w; dst = wcat + (size_t)2048 * 512; C = 256; tile = b - 1024; }
  else { src = v_w1; dst = wcat + (size_t)2304 * 512; C = 256; tile = b - 1152; }
  const int R = 512;
  const int tpc = C >> 5;
  const int c0 = (tile % tpc) * 32, r0 = (tile / tpc) * 32;
  const int tx = tid & 31, ty = tid >> 5;
#pragma unroll
  for (int i = 0; i < 4; ++i) {
    int r = r0 + ty + i * 8;
    t[ty + i * 8][tx] = src[(size_t)r * C + c0 + tx];
  }
  __syncthreads();
#pragma unroll
  for (int i = 0; i < 4; ++i) {
    int c = c0 + ty + i * 8;
    dst[(size_t)c * R + r0 + tx] = f2bfu(t[tx][ty + i * 8]);
  }
}

// ---------------- Kernel B: fat = S-GEMM (compute) + w12/wf2 transposes (BW) -------------
// [0,1280): S-GEMM 128-tile bf16 (M=8192,N=2560,K=512), relu except [2048,2304);
//           cols<1024 -> fp8 a8, else bf16 ocat.
// [1280,9472): w8T fp8 transpose (PERM n'=e*32+a) of hw1_w2 [1024][8192].
// [9472,9728): wf2T bf16 transpose of hwf_w2 [1024][256].
#define FATB_BLOCKS 9728
__global__ __launch_bounds__(256, 2) void fatB_kernel(
    const unsigned short* __restrict__ st_bf, const unsigned short* __restrict__ wcat,
    const float* __restrict__ bcatp, unsigned short* __restrict__ ocat,
    unsigned char* __restrict__ a8, const float* __restrict__ hw1_w2,
    const float* __restrict__ hwf_w2, unsigned char* __restrict__ w8T,
    unsigned short* __restrict__ wf2T) {
  __shared__ __align__(16) unsigned char smem[32768];
  const int tid = threadIdx.x;
  int b = blockIdx.x;
  if (b < 1280) {  // ---- S-GEMM (m97 2-phase structure) ----
    unsigned short* As = (unsigned short*)smem;
    unsigned short* Bs = (unsigned short*)(smem + 16384);
    const int w = tid >> 6, l = tid & 63;
    const int wr = w >> 1, wc = w & 1;
    const int col0 = (b % 20) * 128, row0 = (b / 20) * 128;
    const int K = 512, N = 2560, Astr = 512;
    f32x4 acc[4][4] = {};
    for (int k0 = 0; k0 < K; k0 += 64) {
      __syncthreads();
#pragma unroll
      for (int i = 0; i < 4; ++i) {
        int cbase = i * 256 + w * 64;
        int c = cbase + l;
        int r = c >> 3, kc = c & 7;
        const unsigned short* src = st_bf + (size_t)(row0 + r) * Astr + (k0 + kc * 8);
        __builtin_amdgcn_global_load_lds((const as1_void*)src, (as3_void*)&As[cbase * 8], 16, 0, 0);
      }
#pragma unroll
      for (int i = 0; i < 4; ++i) {
        int cbase = i * 256 + w * 64;
        int c = cbase + l;
        int r = c >> 3, kc = c & 7;
        const unsigned short* src = wcat + (size_t)(col0 + r) * K + (k0 + kc * 8);
        __builtin_amdgcn_global_load_lds((const as1_void*)src, (as3_void*)&Bs[cbase * 8], 16, 0, 0);
      }
      __syncthreads();
#pragma unroll
      for (int kk = 0; kk < 2; ++kk) {
        bf16x8 af[4], bfr[4];
#pragma unroll
        for (int i = 0; i < 4; ++i)
          af[i] = *(const bf16x8*)&As[(wr * 64 + i * 16 + (l & 15)) * 64 + kk * 32 + (l >> 4) * 8];
#pragma unroll
        for (int j = 0; j < 4; ++j)
          bfr[j] = *(const bf16x8*)&Bs[(wc * 64 + j * 16 + (l & 15)) * 64 + kk * 32 + (l >> 4) * 8];
#pragma unroll
        for (int i = 0; i < 4; ++i)
#pragma unroll
          for (int j = 0; j < 4; ++j)
            acc[i][j] = __builtin_amdgcn_mfma_f32_16x16x32_bf16(af[i], bfr[j], acc[i][j], 0, 0, 0);
      }
    }
#pragma unroll
    for (int i = 0; i < 4; ++i)
#pragma unroll
      for (int j = 0; j < 4; ++j)
#pragma unroll
        for (int t = 0; t < 4; ++t) {
          int r = row0 + wr * 64 + i * 16 + (l >> 4) * 4 + t;
          int c = col0 + wc * 64 + j * 16 + (l & 15);
          float v = acc[i][j][t] + bcatp[c];
          if (!(c >= 2048 && c < 2304)) v = fmaxf(v, 0.0f);
          if (c < 1024)
            a8[(size_t)r * 1024 + c] = f2fp8(v);
          else
            ocat[(size_t)r * N + c] = f2bfu(v);
        }
    return;
  }
  b -= 1280;
  {  // ---- transposes (BW-bound riders) ----
    float(*t)[33] = (float(*)[33])smem;
    const float* src;
    int C, tile;
    bool perm;
    if (b < 8192) { src = hw1_w2; C = 8192; tile = b; perm = true; }
    else { src = hwf_w2; C = 256; tile = b - 8192; perm = false; }
    const int R = 1024;
    const int tpc = C >> 5;
    const int c0 = (tile % tpc) * 32, r0 = (tile / tpc) * 32;
    const int tx = tid & 31, ty = tid >> 5;
#pragma unroll
    for (int i = 0; i < 4; ++i) {
      int r = r0 + ty + i * 8;
      t[ty + i * 8][tx] = src[(size_t)r * C + c0 + tx];
    }
    __syncthreads();
#pragma unroll
    for (int i = 0; i < 4; ++i) {
      int c = c0 + ty + i * 8;
      if (perm) {
        size_t co = (size_t)(((c & 255) << 5) + (c >> 8));
        w8T[co * 1024 + r0 + tx] = f2fp8(t[tx][ty + i * 8]);
      } else {
        wf2T[(size_t)c * R + r0 + tx] = f2bfu(t[tx][ty + i * 8]);
      }
    }
  }
}

// ---------------- Kernel C: fat = wf-GEMM (small) + MX-fp8 big GEMM ----------------------
// [0,128): wf-GEMM 128-tile bf16: w_final = |hf @ hwf_w2 + b| (A = ocat+1024, strided).
// [128,4224): 128x128 MX-fp8 K=128 GEMM (m148 recipe) + fused |.| + agent contraction.
#define FATC_BLOCKS 4224
__global__ __launch_bounds__(256, 2) void fatC_kernel(
    const unsigned short* __restrict__ ocat, const unsigned short* __restrict__ wf2T,
    const float* __restrict__ hwf_b2, unsigned short* __restrict__ wfb,
    const unsigned char* __restrict__ a8, const unsigned char* __restrict__ w8T,
    const float* __restrict__ bias_p, const float* __restrict__ qs,
    float* __restrict__ hid) {
  __shared__ __align__(16) unsigned char smem[32768];
  const int tid = threadIdx.x;
  int b = blockIdx.x;
  const int w = tid >> 6, l = tid & 63;
  const int wr = w >> 1, wc = w & 1;
  if (b < 128) {  // ---- wf-GEMM (m97 2-phase, bf16, abs epilogue) ----
    unsigned short* As = (unsigned short*)smem;
    unsigned short* Bs = (unsigned short*)(smem + 16384);
    const int col0 = (b & 1) * 128, row0 = (b >> 1) * 128;
    const int K = 1024, N = 256, Astr = 2560;
    const unsigned short* Ap = ocat + 1024;
    f32x4 acc[4][4] = {};
    for (int k0 = 0; k0 < K; k0 += 64) {
      __syncthreads();
#pragma unroll
      for (int i = 0; i < 4; ++i) {
        int cbase = i * 256 + w * 64;
        int c = cbase + l;
        int r = c >> 3, kc = c & 7;
        const unsigned short* src = Ap + (size_t)(row0 + r) * Astr + (k0 + kc * 8);
        __builtin_amdgcn_global_load_lds((const as1_void*)src, (as3_void*)&As[cbase * 8], 16, 0, 0);
      }
#pragma unroll
      for (int i = 0; i < 4; ++i) {
        int cbase = i * 256 + w * 64;
        int c = cbase + l;
        int r = c >> 3, kc = c & 7;
        const unsigned short* src = wf2T + (size_t)(col0 + r) * K + (k0 + kc * 8);
        __builtin_amdgcn_global_load_lds((const as1_void*)src, (as3_void*)&Bs[cbase * 8], 16, 0, 0);
      }
      __syncthreads();
#pragma unroll
      for (int kk = 0; kk < 2; ++kk) {
        bf16x8 af[4], bfr[4];
#pragma unroll
        for (int i = 0; i < 4; ++i)
          af[i] = *(const bf16x8*)&As[(wr * 64 + i * 16 + (l & 15)) * 64 + kk * 32 + (l >> 4) * 8];
#pragma unroll
        for (int j = 0; j < 4; ++j)
          bfr[j] = *(const bf16x8*)&Bs[(wc * 64 + j * 16 + (l & 15)) * 64 + kk * 32 + (l >> 4) * 8];
#pragma unroll
        for (int i = 0; i < 4; ++i)
#pragma unroll
          for (int j = 0; j < 4; ++j)
            acc[i][j] = __builtin_amdgcn_mfma_f32_16x16x32_bf16(af[i], bfr[j], acc[i][j], 0, 0, 0);
      }
    }
#pragma unroll
    for (int i = 0; i < 4; ++i)
#pragma unroll
      for (int j = 0; j < 4; ++j)
#pragma unroll
        for (int t = 0; t < 4; ++t) {
          int r = row0 + wr * 64 + i * 16 + (l >> 4) * 4 + t;
          int c = col0 + wc * 64 + j * 16 + (l & 15);
          float v = fabsf(acc[i][j][t] + hwf_b2[c]);
          wfb[(size_t)r * N + c] = f2bfu(v);
        }
    return;
  }
  b -= 128;
  {  // ---- MX-fp8 big GEMM (m148 recipe) + fused agent contraction ----
    unsigned char* As = smem;
    unsigned char* Bs = smem + 16384;
    const int col0 = (b & 63) * 128, row0 = (b >> 6) * 128;
    const int K = 1024;
    f32x4 acc[4][4] = {};
    for (int k0 = 0; k0 < K; k0 += 128) {
      __syncthreads();
#pragma unroll
      for (int i = 0; i < 4; ++i) {
        int cbase = i * 256 + w * 64;
        int c = cbase + l;
        int r = c >> 3, kc = c & 7;
        const unsigned char* src = a8 + (size_t)(row0 + r) * K + (k0 + ((kc ^ (r & 7)) << 4));
        __builtin_amdgcn_global_load_lds((const as1_void*)src, (as3_void*)&As[cbase * 16], 16, 0, 0);
      }
#pragma unroll
      for (int i = 0; i < 4; ++i) {
        int cbase = i * 256 + w * 64;
        int c = cbase + l;
        int r = c >> 3, kc = c & 7;
        const unsigned char* src = w8T + (size_t)(col0 + r) * K + (k0 + ((kc ^ (r & 7)) << 4));
        __builtin_amdgcn_global_load_lds((const as1_void*)src, (as3_void*)&Bs[cbase * 16], 16, 0, 0);
      }
      __syncthreads();
      i32x8 af[4], bfr[4];
#pragma unroll
      for (int i = 0; i < 4; ++i) {
        const int r = wr * 64 + i * 16 + (l & 15);
        const int kc = (l >> 4) * 2;
        i32x4 lo = *(const i32x4*)&As[r * 128 + ((kc ^ (r & 7)) << 4)];
        i32x4 hi = *(const i32x4*)&As[r * 128 + (((kc + 1) ^ (r & 7)) << 4)];
        af[i] = __builtin_shufflevector(lo, hi, 0, 1, 2, 3, 4, 5, 6, 7);
      }
#pragma unroll
      for (int j = 0; j < 4; ++j) {
        const int r = wc * 64 + j * 16 + (l & 15);
        const int kc = (l >> 4) * 2;
        i32x4 lo = *(const i32x4*)&Bs[r * 128 + ((kc ^ (r & 7)) << 4)];
        i32x4 hi = *(const i32x4*)&Bs[r * 128 + (((kc + 1) ^ (r & 7)) << 4)];
        bfr[j] = __builtin_shufflevector(lo, hi, 0, 1, 2, 3, 4, 5, 6, 7);
      }
      __builtin_amdgcn_s_setprio(1);
#pragma unroll
      for (int i = 0; i < 4; ++i)
#pragma unroll
        for (int j = 0; j < 4; ++j)
          acc[i][j] = __builtin_amdgcn_mfma_scale_f32_16x16x128_f8f6f4(
              af[i], bfr[j], acc[i][j], 0, 0, 0, 127, 0, 127);
      __builtin_amdgcn_s_setprio(0);
    }

    // agent-contraction epilogue (cols permuted n'=e*32+a)
    float qv[4][4][2];
    float bp[4];
#pragma unroll
    for (int i = 0; i < 4; ++i)
#pragma unroll
      for (int tt = 0; tt < 4; ++tt) {
        const int r = row0 + wr * 64 + i * 16 + (l >> 4) * 4 + tt;
        qv[i][tt][0] = qs[(size_t)r * A_DIM + (l & 15)];
        qv[i][tt][1] = qs[(size_t)r * A_DIM + 16 + (l & 15)];
      }
#pragma unroll
    for (int j = 0; j < 4; ++j)
      bp[j] = bias_p[col0 + wc * 64 + j * 16 + (l & 15)];
#pragma unroll
    for (int i = 0; i < 4; ++i)
#pragma unroll
      for (int e2 = 0; e2 < 2; ++e2) {
        const int e = (col0 >> 5) + wc * 2 + e2;
#pragma unroll
        for (int tt = 0; tt < 4; ++tt) {
          const int r = row0 + wr * 64 + i * 16 + (l >> 4) * 4 + tt;
          float s = fmaf(qv[i][tt][0], fabsf(acc[i][e2 * 2][tt] + bp[e2 * 2]), 0.0f);
          s = fmaf(qv[i][tt][1], fabsf(acc[i][e2 * 2 + 1][tt] + bp[e2 * 2 + 1]), s);
          s = row16_sum(s);
          if ((l & 15) == 0) hid[(size_t)r * E_DIM + e] = s;
        }
      }
  }
}

// tiny final pass: out[b] = sum_e elu(hid+b1)*wf + sum_e vh*vw2 + vb2
__global__ void final2_kernel(const float* __restrict__ hid, const unsigned short* __restrict__ b1p,
                              const unsigned short* __restrict__ vhp, int ostr,
                              const unsigned short* __restrict__ wf,
                              const float* __restrict__ vw2, const float* __restrict__ vb2,
                              float* __restrict__ out) {
  const int tid = threadIdx.x;  // e
  const int b = blockIdx.x;
  float h = hid[(size_t)b * E_DIM + tid] + bf2f(b1p[(size_t)b * ostr + tid]);
  float hidden = h > 0.0f ? h : (expf(h) - 1.0f);  // elu
  float s = hidden * bf2f(wf[(size_t)b * E_DIM + tid]) +
            bf2f(vhp[(size_t)b * ostr + tid]) * vw2[tid];
  __shared__ float red[4];
#pragma unroll
  for (int o = 32; o > 0; o >>= 1) s += __shfl_down(s, o, 64);
  if ((tid & 63) == 0) red[tid >> 6] = s;
  __syncthreads();
  if (tid == 0) out[b] = red[0] + red[1] + red[2] + red[3] + vb2[0];
}

extern "C" void kernel_launch(void* const* d_in, const int* in_sizes, int n_in,
                              void* d_out, int out_size, void* d_ws, size_t ws_size,
                              hipStream_t stream) {
  const float* agent_qs = (const float*)d_in[0];
  const float* states = (const float*)d_in[1];
  const float* hw1_w1 = (const float*)d_in[2];
  const float* hw1_b1 = (const float*)d_in[3];
  const float* hw1_w2 = (const float*)d_in[4];
  const float* hw1_b2 = (const float*)d_in[5];
  const float* hb1_w = (const float*)d_in[6];
  const float* hb1_b = (const float*)d_in[7];
  const float* hwf_w1 = (const float*)d_in[8];
  const float* hwf_b1 = (const float*)d_in[9];
  const float* hwf_w2 = (const float*)d_in[10];
  const float* hwf_b2 = (const float*)d_in[11];
  const float* v_w1 = (const float*)d_in[12];
  const float* v_b1 = (const float*)d_in[13];
  const float* v_w2 = (const float*)d_in[14];
  const float* v_b2 = (const float*)d_in[15];
  float* out = (float*)d_out;

  size_t off = 0;
  char* ws = (char*)d_ws;
  auto carve = [&](size_t bytes) -> void* {
    void* p = ws + off;
    off = (off + bytes + 255) & ~(size_t)255;
    return p;
  };
  const int NCAT = 2560;  // 1024 h1 | 1024 hf | 256 b1 | 256 vh
  unsigned short* st_bf = (unsigned short*)carve((size_t)B_SZ * S_DIM * 2);
  unsigned short* wcat = (unsigned short*)carve((size_t)NCAT * S_DIM * 2);
  unsigned char* w8T = (unsigned char*)carve((size_t)8192 * H_DIM);
  unsigned short* wf2T = (unsigned short*)carve((size_t)E_DIM * H_DIM * 2);
  float* bcatp = (float*)carve((size_t)NCAT * 4);
  float* bias_p = (float*)carve((size_t)8192 * 4);
  unsigned short* ocat = (unsigned short*)carve((size_t)B_SZ * NCAT * 2);  // cols [0,1024) unused
  unsigned char* a8 = (unsigned char*)carve((size_t)B_SZ * H_DIM);
  unsigned short* wfb = (unsigned short*)carve((size_t)B_SZ * E_DIM * 2);
  float* hid = (float*)carve((size_t)B_SZ * E_DIM * 4);

  // A: light prep (st_bf, wcat, bcatp, bias_p)
  prepA_kernel<<<PREPA_BLOCKS, 256, 0, stream>>>(
      states, hw1_w1, hwf_w1, hb1_w, v_w1, hw1_b1, hwf_b1, hb1_b, v_b1, hw1_b2,
      st_bf, wcat, bcatp, bias_p);

  // B: S-GEMM + (w8T fp8 / wf2T bf16) transposes in one dispatch
  fatB_kernel<<<FATB_BLOCKS, 256, 0, stream>>>(
      st_bf, wcat, bcatp, ocat, a8, hw1_w2, hwf_w2, w8T, wf2T);

  // C: wf-GEMM + MX-fp8 big GEMM (fused |.| + agent contraction) in one dispatch
  fatC_kernel<<<FATC_BLOCKS, 256, 0, stream>>>(
      ocat, wf2T, hwf_b2, wfb, a8, w8T, bias_p, agent_qs, hid);

  // D: tiny epilogue
  final2_kernel<<<B_SZ, 256, 0, stream>>>(hid, ocat + 2048, ocat + 2304, NCAT, wfb, v_w2, v_b2, out);
}

// Round 14
// 150.241 us; speedup vs baseline: 5.3134x; 5.3134x over previous
//
#include <hip/hip_runtime.h>
#include <hip/hip_bf16.h>

#define B_SZ 8192
#define S_DIM 512
#define H_DIM 1024
#define E_DIM 256
#define A_DIM 32

typedef __attribute__((ext_vector_type(4))) float f32x4;
typedef __attribute__((ext_vector_type(8))) __bf16 bf16x8;
typedef __attribute__((ext_vector_type(4))) int i32x4;
typedef __attribute__((ext_vector_type(8))) int i32x8;

using as1_void = __attribute__((address_space(1))) void;
using as3_void = __attribute__((address_space(3))) void;

__device__ __forceinline__ unsigned short f2bfu(float f) {
  unsigned u = __builtin_bit_cast(unsigned, f);
  unsigned r = (u + 0x7FFFu + ((u >> 16) & 1u)) >> 16;
  return (unsigned short)r;
}
__device__ __forceinline__ float bf2f(unsigned short x) {
  unsigned u = ((unsigned)x) << 16;
  return __builtin_bit_cast(float, u);
}
// f32 -> OCP e4m3 via HW packed convert (byte 0)
__device__ __forceinline__ unsigned char f2fp8(float f) {
  return (unsigned char)(__builtin_amdgcn_cvt_pk_fp8_f32(f, f, 0, false) & 0xFF);
}

// 16-lane xor-butterfly sum via DPP (VALU pipe, no LDS traffic).
__device__ __forceinline__ float row16_sum(float s) {
  float t;
  t = __builtin_bit_cast(float, __builtin_amdgcn_update_dpp(
          0, __builtin_bit_cast(int, s), 0xB1, 0xF, 0xF, true));
  s += t;
  t = __builtin_bit_cast(float, __builtin_amdgcn_update_dpp(
          0, __builtin_bit_cast(int, s), 0x4E, 0xF, 0xF, true));
  s += t;
  t = __builtin_bit_cast(float, __builtin_amdgcn_update_dpp(
          0, __builtin_bit_cast(int, s), 0x141, 0xF, 0xF, true));
  s += t;
  t = __builtin_bit_cast(float, __builtin_amdgcn_update_dpp(
          0, __builtin_bit_cast(int, s), 0x140, 0xF, 0xF, true));
  s += t;
  return s;
}

// ---------------- Kernel A: light prep (conv + small transposes + bias packs) ------------
#define PREPA_BLOCKS 5418
__global__ void prepA_kernel(const float* __restrict__ states, const float* __restrict__ hw1_w1,
                             const float* __restrict__ hwf_w1, const float* __restrict__ hb1_w,
                             const float* __restrict__ v_w1, const float* __restrict__ hw1_b1,
                             const float* __restrict__ hwf_b1, const float* __restrict__ hb1_b,
                             const float* __restrict__ v_b1, const float* __restrict__ hw1_b2,
                             unsigned short* __restrict__ st_bf, unsigned short* __restrict__ wcat,
                             float* __restrict__ bcatp, float* __restrict__ bias_p) {
  __shared__ float t[32][33];
  const int tid = threadIdx.x;
  int b = blockIdx.x;
  if (b < 4096) {  // conv
    int idx = b * 1024 + tid * 4;
    const float4 v = *(const float4*)(states + idx);
    ushort4 o;
    o.x = f2bfu(v.x); o.y = f2bfu(v.y); o.z = f2bfu(v.z); o.w = f2bfu(v.w);
    *(ushort4*)(st_bf + idx) = o;
    return;
  }
  b -= 4096;
  if (b >= 1280) {  // bias packs
    b -= 1280;
    if (b < 10) {
      int i = b * 256 + tid;
      if (i < 2560) {
        float v;
        if (i < 1024) v = hw1_b1[i];
        else if (i < 2048) v = hwf_b1[i - 1024];
        else if (i < 2304) v = hb1_b[i - 2048];
        else v = v_b1[i - 2304];
        bcatp[i] = v;
      }
    } else {
      int n = (b - 10) * 256 + tid;
      bias_p[n] = hw1_b2[((n & 31) << 8) + (n >> 5)];
    }
    return;
  }
  // wcat transposes (K=512 weights -> B^T bf16)
  const float* src;
  unsigned short* dst;
  int C, tile;
  if (b < 512) { src = hw1_w1; dst = wcat; C = 1024; tile = b; }
  else if (b < 1024) { src = hwf_w1; dst = wcat + (size_t)1024 * 512; C = 1024; tile = b - 512; }
  else if (b < 1152) { src = hb1_w; dst = wcat + (size_t)2048 * 512; C = 256; tile = b - 1024; }
  else { src = v_w1; dst = wcat + (size_t)2304 * 512; C = 256; tile = b - 1152; }
  const int R = 512;
  const int tpc = C >> 5;
  const int c0 = (tile % tpc) * 32, r0 = (tile / tpc) * 32;
  const int tx = tid & 31, ty = tid >> 5;
#pragma unroll
  for (int i = 0; i < 4; ++i) {
    int r = r0 + ty + i * 8;
    t[ty + i * 8][tx] = src[(size_t)r * C + c0 + tx];
  }
  __syncthreads();
#pragma unroll
  for (int i = 0; i < 4; ++i) {
    int c = c0 + ty + i * 8;
    dst[(size_t)c * R + r0 + tx] = f2bfu(t[tx][ty + i * 8]);
  }
}

// ---------------- Kernel B: fat = S-GEMM (compute) + w12/wf2 transposes (BW) -------------
// [0,1280): S-GEMM 128-tile bf16 (M=8192,N=2560,K=512), relu except [2048,2304);
//           cols<1024 -> fp8 a8, else bf16 ocat.
// [1280,9472): w8T fp8 transpose (PERM n'=e*32+a); [9472,9728): wf2T bf16 transpose.
#define FATB_BLOCKS 9728
__global__ __launch_bounds__(256, 2) void fatB_kernel(
    const unsigned short* __restrict__ st_bf, const unsigned short* __restrict__ wcat,
    const float* __restrict__ bcatp, unsigned short* __restrict__ ocat,
    unsigned char* __restrict__ a8, const float* __restrict__ hw1_w2,
    const float* __restrict__ hwf_w2, unsigned char* __restrict__ w8T,
    unsigned short* __restrict__ wf2T) {
  __shared__ __align__(16) unsigned char smem[32768];
  const int tid = threadIdx.x;
  int b = blockIdx.x;
  if (b < 1280) {  // ---- S-GEMM (m97 2-phase structure) ----
    unsigned short* As = (unsigned short*)smem;
    unsigned short* Bs = (unsigned short*)(smem + 16384);
    const int w = tid >> 6, l = tid & 63;
    const int wr = w >> 1, wc = w & 1;
    const int col0 = (b % 20) * 128, row0 = (b / 20) * 128;
    const int K = 512, N = 2560, Astr = 512;
    f32x4 acc[4][4] = {};
    for (int k0 = 0; k0 < K; k0 += 64) {
      __syncthreads();
#pragma unroll
      for (int i = 0; i < 4; ++i) {
        int cbase = i * 256 + w * 64;
        int c = cbase + l;
        int r = c >> 3, kc = c & 7;
        const unsigned short* src = st_bf + (size_t)(row0 + r) * Astr + (k0 + kc * 8);
        __builtin_amdgcn_global_load_lds((const as1_void*)src, (as3_void*)&As[cbase * 8], 16, 0, 0);
      }
#pragma unroll
      for (int i = 0; i < 4; ++i) {
        int cbase = i * 256 + w * 64;
        int c = cbase + l;
        int r = c >> 3, kc = c & 7;
        const unsigned short* src = wcat + (size_t)(col0 + r) * K + (k0 + kc * 8);
        __builtin_amdgcn_global_load_lds((const as1_void*)src, (as3_void*)&Bs[cbase * 8], 16, 0, 0);
      }
      __syncthreads();
#pragma unroll
      for (int kk = 0; kk < 2; ++kk) {
        bf16x8 af[4], bfr[4];
#pragma unroll
        for (int i = 0; i < 4; ++i)
          af[i] = *(const bf16x8*)&As[(wr * 64 + i * 16 + (l & 15)) * 64 + kk * 32 + (l >> 4) * 8];
#pragma unroll
        for (int j = 0; j < 4; ++j)
          bfr[j] = *(const bf16x8*)&Bs[(wc * 64 + j * 16 + (l & 15)) * 64 + kk * 32 + (l >> 4) * 8];
#pragma unroll
        for (int i = 0; i < 4; ++i)
#pragma unroll
          for (int j = 0; j < 4; ++j)
            acc[i][j] = __builtin_amdgcn_mfma_f32_16x16x32_bf16(af[i], bfr[j], acc[i][j], 0, 0, 0);
      }
    }
#pragma unroll
    for (int i = 0; i < 4; ++i)
#pragma unroll
      for (int j = 0; j < 4; ++j)
#pragma unroll
        for (int t = 0; t < 4; ++t) {
          int r = row0 + wr * 64 + i * 16 + (l >> 4) * 4 + t;
          int c = col0 + wc * 64 + j * 16 + (l & 15);
          float v = acc[i][j][t] + bcatp[c];
          if (!(c >= 2048 && c < 2304)) v = fmaxf(v, 0.0f);
          if (c < 1024)
            a8[(size_t)r * 1024 + c] = f2fp8(v);
          else
            ocat[(size_t)r * N + c] = f2bfu(v);
        }
    return;
  }
  b -= 1280;
  {  // ---- transposes (BW-bound riders) ----
    float(*t)[33] = (float(*)[33])smem;
    const float* src;
    int C, tile;
    bool perm;
    if (b < 8192) { src = hw1_w2; C = 8192; tile = b; perm = true; }
    else { src = hwf_w2; C = 256; tile = b - 8192; perm = false; }
    const int R = 1024;
    const int tpc = C >> 5;
    const int c0 = (tile % tpc) * 32, r0 = (tile / tpc) * 32;
    const int tx = tid & 31, ty = tid >> 5;
#pragma unroll
    for (int i = 0; i < 4; ++i) {
      int r = r0 + ty + i * 8;
      t[ty + i * 8][tx] = src[(size_t)r * C + c0 + tx];
    }
    __syncthreads();
#pragma unroll
    for (int i = 0; i < 4; ++i) {
      int c = c0 + ty + i * 8;
      if (perm) {
        size_t co = (size_t)(((c & 255) << 5) + (c >> 8));
        w8T[co * 1024 + r0 + tx] = f2fp8(t[tx][ty + i * 8]);
      } else {
        wf2T[(size_t)c * R + r0 + tx] = f2bfu(t[tx][ty + i * 8]);
      }
    }
  }
}

// ---------------- wf-GEMM: 128x128 2-phase bf16, abs epilogue (separate kernel!) ---------
// NOTE (r13 lesson): do NOT merge two MFMA-accumulator kernels into one branchy kernel —
// the allocator unions the branches, blows the 256-VGPR budget, spills GBs to scratch.
__global__ void wf_gemm_kernel(const unsigned short* __restrict__ A, int Astr,
                               const unsigned short* __restrict__ BT,
                               const float* __restrict__ bias, unsigned short* __restrict__ Cp,
                               int M, int N, int K) {
  __shared__ unsigned short As[128 * 64];
  __shared__ unsigned short Bs[128 * 64];
  const int tid = threadIdx.x;
  const int w = tid >> 6, l = tid & 63;
  const int wr = w >> 1, wc = w & 1;
  const int row0 = blockIdx.y * 128, col0 = blockIdx.x * 128;
  f32x4 acc[4][4] = {};
  for (int k0 = 0; k0 < K; k0 += 64) {
    __syncthreads();
#pragma unroll
    for (int i = 0; i < 4; ++i) {
      int cbase = i * 256 + w * 64;
      int c = cbase + l;
      int r = c >> 3, kc = c & 7;
      const unsigned short* src = A + (size_t)(row0 + r) * Astr + (k0 + kc * 8);
      __builtin_amdgcn_global_load_lds((const as1_void*)src, (as3_void*)&As[cbase * 8], 16, 0, 0);
    }
#pragma unroll
    for (int i = 0; i < 4; ++i) {
      int cbase = i * 256 + w * 64;
      int c = cbase + l;
      int r = c >> 3, kc = c & 7;
      const unsigned short* src = BT + (size_t)(col0 + r) * K + (k0 + kc * 8);
      __builtin_amdgcn_global_load_lds((const as1_void*)src, (as3_void*)&Bs[cbase * 8], 16, 0, 0);
    }
    __syncthreads();
#pragma unroll
    for (int kk = 0; kk < 2; ++kk) {
      bf16x8 af[4], bfr[4];
#pragma unroll
      for (int i = 0; i < 4; ++i)
        af[i] = *(const bf16x8*)&As[(wr * 64 + i * 16 + (l & 15)) * 64 + kk * 32 + (l >> 4) * 8];
#pragma unroll
      for (int j = 0; j < 4; ++j)
        bfr[j] = *(const bf16x8*)&Bs[(wc * 64 + j * 16 + (l & 15)) * 64 + kk * 32 + (l >> 4) * 8];
#pragma unroll
      for (int i = 0; i < 4; ++i)
#pragma unroll
        for (int j = 0; j < 4; ++j)
          acc[i][j] = __builtin_amdgcn_mfma_f32_16x16x32_bf16(af[i], bfr[j], acc[i][j], 0, 0, 0);
    }
  }
#pragma unroll
  for (int i = 0; i < 4; ++i)
#pragma unroll
    for (int j = 0; j < 4; ++j)
#pragma unroll
      for (int t = 0; t < 4; ++t) {
        int r = row0 + wr * 64 + i * 16 + (l >> 4) * 4 + t;
        int c = col0 + wc * 64 + j * 16 + (l & 15);
        Cp[(size_t)r * N + c] = f2bfu(fabsf(acc[i][j][t] + bias[c]));
      }
}

// ---------------- 128x128 MX-fp8 K=128 GEMM (r12-verbatim, 84 VGPR, no spill) ------------
// m97 2-barrier structure, BK=128, 256 threads, 32 KB LDS -> ~3 blocks/CU overlap.
// Epilogue (cols permuted n'=e*32+a): e=(col0>>5)+wc*2+e2, a=(e2-half<<4)+(l&15);
// j-pair sum + 16-lane DPP butterfly; lane (l&15)==0 writes hid[r][e] f32.
__global__ __launch_bounds__(256, 2) void gemm128_f8(
    const unsigned char* __restrict__ A, const unsigned char* __restrict__ BT,
    const float* __restrict__ bias, const float* __restrict__ qs,
    float* __restrict__ hid, int M, int N, int K) {
  __shared__ __align__(16) unsigned char As[128 * 128];
  __shared__ __align__(16) unsigned char Bs[128 * 128];
  const int tid = threadIdx.x;
  const int w = tid >> 6, l = tid & 63;
  const int wr = w >> 1, wc = w & 1;
  const int row0 = blockIdx.y * 128, col0 = blockIdx.x * 128;
  f32x4 acc[4][4] = {};
  for (int k0 = 0; k0 < K; k0 += 128) {
    __syncthreads();
#pragma unroll
    for (int i = 0; i < 4; ++i) {
      int cbase = i * 256 + w * 64;
      int c = cbase + l;
      int r = c >> 3, kc = c & 7;  // 8 x 16B chunks per 128-fp8 row
      const unsigned char* src = A + (size_t)(row0 + r) * K + (k0 + ((kc ^ (r & 7)) << 4));
      __builtin_amdgcn_global_load_lds((const as1_void*)src, (as3_void*)&As[cbase * 16], 16, 0, 0);
    }
#pragma unroll
    for (int i = 0; i < 4; ++i) {
      int cbase = i * 256 + w * 64;
      int c = cbase + l;
      int r = c >> 3, kc = c & 7;
      const unsigned char* src = BT + (size_t)(col0 + r) * K + (k0 + ((kc ^ (r & 7)) << 4));
      __builtin_amdgcn_global_load_lds((const as1_void*)src, (as3_void*)&Bs[cbase * 16], 16, 0, 0);
    }
    __syncthreads();
    i32x8 af[4], bfr[4];
#pragma unroll
    for (int i = 0; i < 4; ++i) {
      const int r = wr * 64 + i * 16 + (l & 15);
      const int kc = (l >> 4) * 2;
      i32x4 lo = *(const i32x4*)&As[r * 128 + ((kc ^ (r & 7)) << 4)];
      i32x4 hi = *(const i32x4*)&As[r * 128 + (((kc + 1) ^ (r & 7)) << 4)];
      af[i] = __builtin_shufflevector(lo, hi, 0, 1, 2, 3, 4, 5, 6, 7);
    }
#pragma unroll
    for (int j = 0; j < 4; ++j) {
      const int r = wc * 64 + j * 16 + (l & 15);
      const int kc = (l >> 4) * 2;
      i32x4 lo = *(const i32x4*)&Bs[r * 128 + ((kc ^ (r & 7)) << 4)];
      i32x4 hi = *(const i32x4*)&Bs[r * 128 + (((kc + 1) ^ (r & 7)) << 4)];
      bfr[j] = __builtin_shufflevector(lo, hi, 0, 1, 2, 3, 4, 5, 6, 7);
    }
    __builtin_amdgcn_s_setprio(1);
#pragma unroll
    for (int i = 0; i < 4; ++i)
#pragma unroll
      for (int j = 0; j < 4; ++j)
        acc[i][j] = __builtin_amdgcn_mfma_scale_f32_16x16x128_f8f6f4(
            af[i], bfr[j], acc[i][j], 0, 0, 0, 127, 0, 127);
    __builtin_amdgcn_s_setprio(0);
  }

  // agent-contraction epilogue: hoist qs/bias to registers, j-pair sum + DPP butterfly.
  float qv[4][4][2];
  float bp[4];
#pragma unroll
  for (int i = 0; i < 4; ++i)
#pragma unroll
    for (int tt = 0; tt < 4; ++tt) {
      const int r = row0 + wr * 64 + i * 16 + (l >> 4) * 4 + tt;
      qv[i][tt][0] = qs[(size_t)r * A_DIM + (l & 15)];
      qv[i][tt][1] = qs[(size_t)r * A_DIM + 16 + (l & 15)];
    }
#pragma unroll
  for (int j = 0; j < 4; ++j)
    bp[j] = bias[col0 + wc * 64 + j * 16 + (l & 15)];
#pragma unroll
  for (int i = 0; i < 4; ++i)
#pragma unroll
    for (int e2 = 0; e2 < 2; ++e2) {
      const int e = (col0 >> 5) + wc * 2 + e2;
#pragma unroll
      for (int tt = 0; tt < 4; ++tt) {
        const int r = row0 + wr * 64 + i * 16 + (l >> 4) * 4 + tt;
        float s = fmaf(qv[i][tt][0], fabsf(acc[i][e2 * 2][tt] + bp[e2 * 2]), 0.0f);
        s = fmaf(qv[i][tt][1], fabsf(acc[i][e2 * 2 + 1][tt] + bp[e2 * 2 + 1]), s);
        s = row16_sum(s);
        if ((l & 15) == 0) hid[(size_t)r * E_DIM + e] = s;
      }
    }
}

// tiny final pass: out[b] = sum_e elu(hid+b1)*wf + sum_e vh*vw2 + vb2
__global__ void final2_kernel(const float* __restrict__ hid, const unsigned short* __restrict__ b1p,
                              const unsigned short* __restrict__ vhp, int ostr,
                              const unsigned short* __restrict__ wf,
                              const float* __restrict__ vw2, const float* __restrict__ vb2,
                              float* __restrict__ out) {
  const int tid = threadIdx.x;  // e
  const int b = blockIdx.x;
  float h = hid[(size_t)b * E_DIM + tid] + bf2f(b1p[(size_t)b * ostr + tid]);
  float hidden = h > 0.0f ? h : (expf(h) - 1.0f);  // elu
  float s = hidden * bf2f(wf[(size_t)b * E_DIM + tid]) +
            bf2f(vhp[(size_t)b * ostr + tid]) * vw2[tid];
  __shared__ float red[4];
#pragma unroll
  for (int o = 32; o > 0; o >>= 1) s += __shfl_down(s, o, 64);
  if ((tid & 63) == 0) red[tid >> 6] = s;
  __syncthreads();
  if (tid == 0) out[b] = red[0] + red[1] + red[2] + red[3] + vb2[0];
}

extern "C" void kernel_launch(void* const* d_in, const int* in_sizes, int n_in,
                              void* d_out, int out_size, void* d_ws, size_t ws_size,
                              hipStream_t stream) {
  const float* agent_qs = (const float*)d_in[0];
  const float* states = (const float*)d_in[1];
  const float* hw1_w1 = (const float*)d_in[2];
  const float* hw1_b1 = (const float*)d_in[3];
  const float* hw1_w2 = (const float*)d_in[4];
  const float* hw1_b2 = (const float*)d_in[5];
  const float* hb1_w = (const float*)d_in[6];
  const float* hb1_b = (const float*)d_in[7];
  const float* hwf_w1 = (const float*)d_in[8];
  const float* hwf_b1 = (const float*)d_in[9];
  const float* hwf_w2 = (const float*)d_in[10];
  const float* hwf_b2 = (const float*)d_in[11];
  const float* v_w1 = (const float*)d_in[12];
  const float* v_b1 = (const float*)d_in[13];
  const float* v_w2 = (const float*)d_in[14];
  const float* v_b2 = (const float*)d_in[15];
  float* out = (float*)d_out;

  size_t off = 0;
  char* ws = (char*)d_ws;
  auto carve = [&](size_t bytes) -> void* {
    void* p = ws + off;
    off = (off + bytes + 255) & ~(size_t)255;
    return p;
  };
  const int NCAT = 2560;  // 1024 h1 | 1024 hf | 256 b1 | 256 vh
  unsigned short* st_bf = (unsigned short*)carve((size_t)B_SZ * S_DIM * 2);
  unsigned short* wcat = (unsigned short*)carve((size_t)NCAT * S_DIM * 2);
  unsigned char* w8T = (unsigned char*)carve((size_t)8192 * H_DIM);
  unsigned short* wf2T = (unsigned short*)carve((size_t)E_DIM * H_DIM * 2);
  float* bcatp = (float*)carve((size_t)NCAT * 4);
  float* bias_p = (float*)carve((size_t)8192 * 4);
  unsigned short* ocat = (unsigned short*)carve((size_t)B_SZ * NCAT * 2);  // cols [0,1024) unused
  unsigned char* a8 = (unsigned char*)carve((size_t)B_SZ * H_DIM);
  unsigned short* wfb = (unsigned short*)carve((size_t)B_SZ * E_DIM * 2);
  float* hid = (float*)carve((size_t)B_SZ * E_DIM * 4);

  // A: light prep (st_bf, wcat, bcatp, bias_p)
  prepA_kernel<<<PREPA_BLOCKS, 256, 0, stream>>>(
      states, hw1_w1, hwf_w1, hb1_w, v_w1, hw1_b1, hwf_b1, hb1_b, v_b1, hw1_b2,
      st_bf, wcat, bcatp, bias_p);

  // B: S-GEMM + (w8T fp8 / wf2T bf16) transposes in one dispatch
  fatB_kernel<<<FATB_BLOCKS, 256, 0, stream>>>(
      st_bf, wcat, bcatp, ocat, a8, hw1_w2, hwf_w2, w8T, wf2T);

  // C1: wf-GEMM (separate kernel — see r13 spill lesson)
  wf_gemm_kernel<<<dim3(E_DIM / 128, B_SZ / 128), 256, 0, stream>>>(
      ocat + 1024, NCAT, wf2T, hwf_b2, wfb, B_SZ, E_DIM, H_DIM);

  // C2: MX-fp8 big GEMM with fused |.| + agent contraction (r12-verbatim)
  gemm128_f8<<<dim3(8192 / 128, B_SZ / 128), 256, 0, stream>>>(
      a8, w8T, bias_p, agent_qs, hid, B_SZ, 8192, H_DIM);

  // D: tiny epilogue
  final2_kernel<<<B_SZ, 256, 0, stream>>>(hid, ocat + 2048, ocat + 2304, NCAT, wfb, v_w2, v_b2, out);
}